// Round 10
// baseline (153.313 us; speedup 1.0000x reference)
//
#include <hip/hip_runtime.h>

// Problem constants
#define LSEQ 1024
#define DMODEL 1024
#define NHEADS 16
#define FDIM 16
#define HDIM 64
#define CHUNK 64
#define NCHUNK 16

typedef __attribute__((ext_vector_type(8))) short short8;   // 8 bf16 (4 VGPRs)
typedef __attribute__((ext_vector_type(4))) float floatx4;  // MFMA acc

__device__ __forceinline__ float bf2f(unsigned short u) {
    unsigned int x = ((unsigned int)u) << 16;
    return __builtin_bit_cast(float, x);
}
__device__ __forceinline__ unsigned short f2bf(float f) {
    unsigned int x = __builtin_bit_cast(unsigned int, f);
    unsigned int r = (x + 0x7fffu + ((x >> 16) & 1u)) >> 16;
    return (unsigned short)r;
}

// Per-block dtype detector (see R5 notes). Returns 1 if inputs are fp32.
__device__ __forceinline__ int block_detect_fp32(const unsigned short* wq) {
    __shared__ int cnt;
    if (threadIdx.x == 0) cnt = 0;
    __syncthreads();
    int bad = 0;
    for (int i = threadIdx.x; i < 1024; i += blockDim.x) {
        int e = (wq[i] >> 7) & 0xFF;
        if (e >= 143 || (e > 0 && e <= 80)) bad++;
    }
    if (bad) atomicAdd(&cnt, bad);
    __syncthreads();
    return cnt > 128;
}

// Workspace layout:
// ushort region (ushort idx):
//   qbB @0        (262144)   bf16 q [1024][256]
//   kbB @262144   (262144)   bf16 k [1024][256]
//   vbB @524288   (1048576)  bf16 v [1024][1024]
// float region (float idx, starts at 786432 = 1572864 ushorts):
//   num0 @786432   (1048576)  fp32 partial numerator, s=0  [1024][1024]
//   num1 @1835008  (1048576)  fp32 partial numerator, s=1
//   den0 @2883584  (16384)    fp32 partial denominator, s=0 [1024][16]
//   den1 @2899968  (16384)
#define U_QB   0
#define U_KB   262144
#define U_VB   524288
#define F_NUM0 786432
#define F_NUM1 1835008
#define F_DEN0 2883584
#define F_DEN1 2899968
#define F_END  2916352

#define MFMA(a, b, c) __builtin_amdgcn_mfma_f32_16x16x32_bf16((a), (b), (c), 0, 0, 0)

// ---------------------------------------------------------------------------
// Kernel 1: QKV projection, distance-2 pipelined 64x64 GEMM.
// grid (24, 16): nb 0..3 q, 4..7 k, 8..23 v. K-loop fully unrolled so the
// two prefetch register sets resolve statically; loads issue 2 iters ahead
// of their LDS write (~2 MFMA phases of vmcnt cover).
// ---------------------------------------------------------------------------
__global__ __launch_bounds__(256) void qkv_gemm(
    const void* __restrict__ hidR, const void* __restrict__ WqR,
    const void* __restrict__ WkR, const void* __restrict__ WvR,
    unsigned short* __restrict__ qb, unsigned short* __restrict__ kb,
    unsigned short* __restrict__ vb) {
    int fp32 = block_detect_fp32((const unsigned short*)WqR);
    __shared__ __align__(16) unsigned short As[64][136];
    __shared__ __align__(16) unsigned short Bs[64][136];
    int nb = blockIdx.x, mb = blockIdx.y;
    const void* Braw; unsigned short* Cout; int ldc, col0, br0;
    if (nb < 4)      { Braw = WqR; br0 = nb * 64;       Cout = qb; ldc = 256;  col0 = nb * 64; }
    else if (nb < 8) { Braw = WkR; br0 = (nb - 4) * 64; Cout = kb; ldc = 256;  col0 = (nb - 4) * 64; }
    else             { Braw = WvR; br0 = (nb - 8) * 64; Cout = vb; ldc = 1024; col0 = (nb - 8) * 64; }

    int t = threadIdx.x;
    int r = t >> 2, c0 = (t & 3) * 32;
    int wave = t >> 6, lane = t & 63;
    int ml = lane & 15, q4 = lane >> 4;
    int mq = (wave >> 1) * 32, nq = (wave & 1) * 32;
    floatx4 acc[4];
    #pragma unroll
    for (int i = 0; i < 4; ++i) acc[i] = (floatx4){0.f, 0.f, 0.f, 0.f};

    short8 av[2][4], bv[2][4];
    auto stage = [&](int k0, short8 a[4], short8 b[4]) {
        if (!fp32) {
            const unsigned short* Ap = (const unsigned short*)hidR + (size_t)(mb * 64 + r) * DMODEL + k0 + c0;
            const unsigned short* Bp = (const unsigned short*)Braw + (size_t)(br0 + r) * DMODEL + k0 + c0;
            #pragma unroll
            for (int j = 0; j < 4; ++j) {
                a[j] = *(const short8*)(Ap + j * 8);
                b[j] = *(const short8*)(Bp + j * 8);
            }
        } else {
            const float* Ap = (const float*)hidR + (size_t)(mb * 64 + r) * DMODEL + k0 + c0;
            const float* Bp = (const float*)Braw + (size_t)(br0 + r) * DMODEL + k0 + c0;
            #pragma unroll
            for (int j = 0; j < 4; ++j)
                #pragma unroll
                for (int u = 0; u < 8; ++u) {
                    a[j][u] = (short)f2bf(Ap[j * 8 + u]);
                    b[j][u] = (short)f2bf(Bp[j * 8 + u]);
                }
        }
    };

    stage(0, av[0], bv[0]);
    stage(128, av[1], bv[1]);
    #pragma unroll
    for (int it = 0; it < 8; ++it) {
        int pp = it & 1;
        __syncthreads();   // previous iter's LDS reads done
        #pragma unroll
        for (int j = 0; j < 4; ++j) {
            *(short8*)&As[r][c0 + j * 8] = av[pp][j];
            *(short8*)&Bs[r][c0 + j * 8] = bv[pp][j];
        }
        __syncthreads();   // LDS ready
        if (it < 6) stage((it + 2) * 128, av[pp], bv[pp]);   // distance-2 prefetch
        #pragma unroll
        for (int kk = 0; kk < 4; ++kk) {
            short8 a0 = *(const short8*)&As[mq + ml][kk * 32 + q4 * 8];
            short8 a1 = *(const short8*)&As[mq + 16 + ml][kk * 32 + q4 * 8];
            short8 b0 = *(const short8*)&Bs[nq + ml][kk * 32 + q4 * 8];
            short8 b1 = *(const short8*)&Bs[nq + 16 + ml][kk * 32 + q4 * 8];
            acc[0] = MFMA(a0, b0, acc[0]); acc[1] = MFMA(a0, b1, acc[1]);
            acc[2] = MFMA(a1, b0, acc[2]); acc[3] = MFMA(a1, b1, acc[3]);
        }
    }
    #pragma unroll
    for (int mi = 0; mi < 2; ++mi)
        #pragma unroll
        for (int ni = 0; ni < 2; ++ni) {
            floatx4 a = acc[mi * 2 + ni];
            int nloc = nq + ni * 16 + ml;
            #pragma unroll
            for (int r4 = 0; r4 < 4; ++r4) {
                int row = mb * 64 + mq + mi * 16 + q4 * 4 + r4;
                Cout[(size_t)row * ldc + col0 + nloc] = f2bf(a[r4]);
            }
        }
}

// ---------------------------------------------------------------------------
// Kernel 2: flash quadratic attention, j-range SPLIT across 2 blocks.
// Block (h, c, s): s=0 handles j in [0,(c+1)/2), s=1 in [(c+1)/2, c].
// Emits UNNORMALIZED fp32 partials (num_s, den_s); out_gemm combines.
// Span halves: worst block = 8 kv-tiles instead of 16. 512 blocks, 2/CU.
// ---------------------------------------------------------------------------
__global__ __launch_bounds__(256) void flash_attn(
    const unsigned short* __restrict__ qb, const unsigned short* __restrict__ kb,
    const unsigned short* __restrict__ vb,
    float* __restrict__ num0, float* __restrict__ num1,
    float* __restrict__ den0, float* __restrict__ den1) {
    int bid = blockIdx.x;
    int h = bid & 15, c = (bid >> 4) & 15, s = bid >> 8;
    int l0 = c * CHUNK;
    int half = (c + 1) >> 1;
    int j0 = s ? half : 0;
    int j1 = s ? (c + 1) : half;   // exclusive
    float* numS = s ? num1 : num0;
    float* denS = s ? den1 : den0;

    __shared__ __align__(16) unsigned short qs[64][40];
    __shared__ __align__(16) unsigned short ksm[64][40];
    __shared__ __align__(16) unsigned short vT[80][72];   // rows 0..63 v^T, 64 ones
    __shared__ __align__(16) unsigned short P[64][72];
    int t = threadIdx.x, lane = t & 63, wave = t >> 6;
    int ml = lane & 15, q4 = lane >> 4;
    int m0 = wave * 16;
    int sm = t >> 2, si4 = (t & 3) * 4, scc = (t & 3) * 16;

    {
        *(ushort4*)&qs[sm][si4] = *(const ushort4*)&qb[(size_t)(l0 + sm) * 256 + h * 16 + si4];
        ushort4 z = {0, 0, 0, 0};
        *(ushort4*)&qs[sm][16 + si4]  = z;
        *(ushort4*)&ksm[sm][16 + si4] = z;   // k pad, persists across tiles
    }
    if (t < 64) {
        vT[64][t] = 0x3F80;   // 1.0 bf16 (denominator row)
        #pragma unroll
        for (int i = 65; i < 80; ++i) vT[i][t] = 0;
    }

    auto load_kv = [&](int j, ushort4& kr, ushort4 vr[4]) {
        kr = *(const ushort4*)&kb[(size_t)(j * 64 + sm) * 256 + h * 16 + si4];
        #pragma unroll
        for (int u = 0; u < 4; ++u)
            vr[u] = *(const ushort4*)&vb[(size_t)(j * 64 + sm) * 1024 + h * 64 + scc + u * 4];
    };

    floatx4 acc[5];
    #pragma unroll
    for (int i = 0; i < 5; ++i) acc[i] = (floatx4){0.f, 0.f, 0.f, 0.f};

    ushort4 kr, vr[4], kr2, vr2[4];
    if (j0 < j1) load_kv(j0, kr, vr);

    for (int j = j0; j < j1; ++j) {
        {
            *(ushort4*)&ksm[sm][si4] = kr;
            unsigned short tmp[16];
            #pragma unroll
            for (int u = 0; u < 4; ++u) *(ushort4*)&tmp[u * 4] = vr[u];
            #pragma unroll
            for (int u = 0; u < 16; ++u) vT[scc + u][sm] = tmp[u];
        }
        __syncthreads();   // staging visible
        if (j + 1 < j1) load_kv(j + 1, kr2, vr2);   // overlap with MFMAs

        short8 aq = *(const short8*)&qs[m0 + ml][q4 * 8];
        bool diag = (j == c);
        #pragma unroll
        for (int nt = 0; nt < 4; ++nt) {
            short8 bk = *(const short8*)&ksm[nt * 16 + ml][q4 * 8];
            floatx4 s4 = {0.f, 0.f, 0.f, 0.f};
            s4 = MFMA(aq, bk, s4);
            int tt = nt * 16 + ml;
            #pragma unroll
            for (int rr = 0; rr < 4; ++rr) {
                int lrow = m0 + q4 * 4 + rr;
                float sv = s4[rr];
                float p = 1.f + 0.25f * sv + 0.03125f * sv * sv;
                if (diag && tt > lrow) p = 0.f;
                P[lrow][tt] = f2bf(p);
            }
        }
        // P rows wave-private: no barrier before PV.
        #pragma unroll
        for (int k0 = 0; k0 < 64; k0 += 32) {
            short8 ap = *(const short8*)&P[m0 + ml][k0 + q4 * 8];
            #pragma unroll
            for (int nt = 0; nt < 5; ++nt) {
                short8 bvv = *(const short8*)&vT[nt * 16 + ml][k0 + q4 * 8];
                acc[nt] = MFMA(ap, bvv, acc[nt]);
            }
        }
        __syncthreads();   // protect ksm/vT from next staging
        kr = kr2;
        #pragma unroll
        for (int u = 0; u < 4; ++u) vr[u] = vr2[u];
    }

    // ---- emit unnormalized fp32 partials (must write even if 0 tiles: ws poisoned)
    #pragma unroll
    for (int rr = 0; rr < 4; ++rr) {
        int lrow = m0 + q4 * 4 + rr;
        float* np = numS + (size_t)(l0 + lrow) * 1024 + h * 64;
        #pragma unroll
        for (int nt = 0; nt < 4; ++nt) np[nt * 16 + ml] = acc[nt][rr];
        if (ml == 0) denS[(size_t)(l0 + lrow) * 16 + h] = acc[4][rr];
    }
}

// ---------------------------------------------------------------------------
// Kernel 3: output projection with fused combine: A = (num0+num1)/(den0+den1)
// packed to bf16 in the staging path; out = A @ Wo^T. Distance-2 pipeline.
// ---------------------------------------------------------------------------
__global__ __launch_bounds__(256) void out_gemm(
    const float* __restrict__ num0, const float* __restrict__ num1,
    const float* __restrict__ den0, const float* __restrict__ den1,
    const void* __restrict__ WoR, void* __restrict__ outv,
    const unsigned short* __restrict__ wqraw) {
    int fp32 = block_detect_fp32(wqraw);
    __shared__ __align__(16) unsigned short As[64][136];
    __shared__ __align__(16) unsigned short Bs[64][136];
    int nb = blockIdx.x, mb = blockIdx.y;
    int br0 = nb * 64;

    int t = threadIdx.x;
    int r = t >> 2, c0 = (t & 3) * 32;
    int wave = t >> 6, lane = t & 63;
    int ml = lane & 15, q4 = lane >> 4;
    int mq = (wave >> 1) * 32, nq = (wave & 1) * 32;
    floatx4 acc[4];
    #pragma unroll
    for (int i = 0; i < 4; ++i) acc[i] = (floatx4){0.f, 0.f, 0.f, 0.f};

    int l = mb * 64 + r;
    short8 av[2][4], bv[2][4];
    auto stage = [&](int k0, short8 a[4], short8 b[4]) {
        int h = (k0 + c0) >> 6;   // 32-col segment sits inside one head
        float den = den0[(size_t)l * 16 + h] + den1[(size_t)l * 16 + h] + 1e-12f;
        float dinv = 1.f / den;
        const float* n0p = num0 + (size_t)l * 1024 + k0 + c0;
        const float* n1p = num1 + (size_t)l * 1024 + k0 + c0;
        #pragma unroll
        for (int j = 0; j < 4; ++j) {
            float4 x0 = *(const float4*)(n0p + j * 8);
            float4 x1 = *(const float4*)(n1p + j * 8);
            float4 y0 = *(const float4*)(n0p + j * 8 + 4);
            float4 y1 = *(const float4*)(n1p + j * 8 + 4);
            a[j][0] = (short)f2bf((x0.x + x1.x) * dinv);
            a[j][1] = (short)f2bf((x0.y + x1.y) * dinv);
            a[j][2] = (short)f2bf((x0.z + x1.z) * dinv);
            a[j][3] = (short)f2bf((x0.w + x1.w) * dinv);
            a[j][4] = (short)f2bf((y0.x + y1.x) * dinv);
            a[j][5] = (short)f2bf((y0.y + y1.y) * dinv);
            a[j][6] = (short)f2bf((y0.z + y1.z) * dinv);
            a[j][7] = (short)f2bf((y0.w + y1.w) * dinv);
        }
        if (!fp32) {
            const unsigned short* Bp = (const unsigned short*)WoR + (size_t)(br0 + r) * DMODEL + k0 + c0;
            #pragma unroll
            for (int j = 0; j < 4; ++j) b[j] = *(const short8*)(Bp + j * 8);
        } else {
            const float* Bp = (const float*)WoR + (size_t)(br0 + r) * DMODEL + k0 + c0;
            #pragma unroll
            for (int j = 0; j < 4; ++j)
                #pragma unroll
                for (int u = 0; u < 8; ++u) b[j][u] = (short)f2bf(Bp[j * 8 + u]);
        }
    };

    stage(0, av[0], bv[0]);
    stage(128, av[1], bv[1]);
    #pragma unroll
    for (int it = 0; it < 8; ++it) {
        int pp = it & 1;
        __syncthreads();
        #pragma unroll
        for (int j = 0; j < 4; ++j) {
            *(short8*)&As[r][c0 + j * 8] = av[pp][j];
            *(short8*)&Bs[r][c0 + j * 8] = bv[pp][j];
        }
        __syncthreads();
        if (it < 6) stage((it + 2) * 128, av[pp], bv[pp]);
        #pragma unroll
        for (int kk = 0; kk < 4; ++kk) {
            short8 a0 = *(const short8*)&As[mq + ml][kk * 32 + q4 * 8];
            short8 a1 = *(const short8*)&As[mq + 16 + ml][kk * 32 + q4 * 8];
            short8 b0 = *(const short8*)&Bs[nq + ml][kk * 32 + q4 * 8];
            short8 b1 = *(const short8*)&Bs[nq + 16 + ml][kk * 32 + q4 * 8];
            acc[0] = MFMA(a0, b0, acc[0]); acc[1] = MFMA(a0, b1, acc[1]);
            acc[2] = MFMA(a1, b0, acc[2]); acc[3] = MFMA(a1, b1, acc[3]);
        }
    }
    #pragma unroll
    for (int mi = 0; mi < 2; ++mi)
        #pragma unroll
        for (int ni = 0; ni < 2; ++ni) {
            floatx4 a = acc[mi * 2 + ni];
            int n = nb * 64 + nq + ni * 16 + ml;
            #pragma unroll
            for (int r4 = 0; r4 < 4; ++r4) {
                int row = mb * 64 + mq + mi * 16 + q4 * 4 + r4;
                size_t idx = (size_t)row * 1024 + n;
                if (fp32) ((float*)outv)[idx] = a[r4];
                else      ((unsigned short*)outv)[idx] = f2bf(a[r4]);
            }
        }
}

// ---------------------------------------------------------------------------
extern "C" void kernel_launch(void* const* d_in, const int* in_sizes, int n_in,
                              void* d_out, int out_size, void* d_ws, size_t ws_size,
                              hipStream_t stream) {
    unsigned short* us = (unsigned short*)d_ws;
    float* ws = (float*)d_ws;
    unsigned short* qbB = us + U_QB;
    unsigned short* kbB = us + U_KB;
    unsigned short* vbB = us + U_VB;
    float* num0 = ws + F_NUM0;
    float* num1 = ws + F_NUM1;
    float* den0 = ws + F_DEN0;
    float* den1 = ws + F_DEN1;
    size_t need = (size_t)F_END * 4ull;
    if (ws_size < need) return;

    qkv_gemm<<<dim3(24, 16), 256, 0, stream>>>(d_in[0], d_in[1], d_in[2], d_in[3], qbB, kbB, vbB);
    flash_attn<<<dim3(512), 256, 0, stream>>>(qbB, kbB, vbB, num0, num1, den0, den1);
    out_gemm<<<dim3(16, 16), 256, 0, stream>>>(num0, num1, den0, den1, d_in[4], d_out,
                                               (const unsigned short*)d_in[1]);
}

// Round 11
// 141.430 us; speedup vs baseline: 1.0840x; 1.0840x over previous
//
#include <hip/hip_runtime.h>

// Problem constants
#define LSEQ 1024
#define DMODEL 1024
#define NHEADS 16
#define FDIM 16
#define HDIM 64
#define CHUNK 64
#define NCHUNK 16

typedef __attribute__((ext_vector_type(8))) short short8;   // 8 bf16 (4 VGPRs)
typedef __attribute__((ext_vector_type(4))) float floatx4;  // MFMA acc

__device__ __forceinline__ float bf2f(unsigned short u) {
    unsigned int x = ((unsigned int)u) << 16;
    return __builtin_bit_cast(float, x);
}
__device__ __forceinline__ unsigned short f2bf(float f) {
    unsigned int x = __builtin_bit_cast(unsigned int, f);
    unsigned int r = (x + 0x7fffu + ((x >> 16) & 1u)) >> 16;
    return (unsigned short)r;
}

// Per-block dtype detector (see R5 notes). Returns 1 if inputs are fp32.
__device__ __forceinline__ int block_detect_fp32(const unsigned short* wq) {
    __shared__ int cnt;
    if (threadIdx.x == 0) cnt = 0;
    __syncthreads();
    int bad = 0;
    for (int i = threadIdx.x; i < 1024; i += blockDim.x) {
        int e = (wq[i] >> 7) & 0xFF;
        if (e >= 143 || (e > 0 && e <= 80)) bad++;
    }
    if (bad) atomicAdd(&cnt, bad);
    __syncthreads();
    return cnt > 128;
}

// Workspace layout (ushort indices):
//   qbB @0        (262144)   bf16 q  [1024][256]
//   kbB @262144   (262144)   bf16 k  [1024][256]
//   vbB @524288   (1048576)  bf16 v  [1024][1024]
//   ybB @1572864  (1048576)  bf16 y  [1024][1024]
#define U_QB   0
#define U_KB   262144
#define U_VB   524288
#define U_YB   1572864

#define MFMA(a, b, c) __builtin_amdgcn_mfma_f32_16x16x32_bf16((a), (b), (c), 0, 0, 0)

// ---------------------------------------------------------------------------
// Distance-2 pipelined 64x64 GEMM tile body: C = A[arow0:+64] @ B[brow0:+64]^T,
// lda = ldb = 1024, K = 1024, BK = 128, fully unrolled 8 iters. Loads for
// iter k+2 issue right after iter k's LDS-ready barrier -> ~2 MFMA phases +
// 1 barrier of vmcnt cover (L2 hit ~200-300 cy). Ping-pong register sets,
// no copies. acc order: 00,01,10,11 (mi*2+ni).
// ---------------------------------------------------------------------------
__device__ __forceinline__ void gemm64_body(
    unsigned short (&As)[64][136], unsigned short (&Bs)[64][136],
    const void* Araw, int a_fp32, int arow0,
    const void* Braw, int b_fp32, int brow0, floatx4 acc[4]) {
    int t = threadIdx.x;
    int r = t >> 2, c0 = (t & 3) * 32;
    int wave = t >> 6, lane = t & 63;
    int ml = lane & 15, q4 = lane >> 4;
    int mq = (wave >> 1) * 32, nq = (wave & 1) * 32;
    #pragma unroll
    for (int i = 0; i < 4; ++i) acc[i] = (floatx4){0.f, 0.f, 0.f, 0.f};

    short8 av[2][4], bv[2][4];
    auto stage = [&](int k0, short8 a[4], short8 b[4]) {
        if (!a_fp32) {
            const unsigned short* Ap = (const unsigned short*)Araw + (size_t)(arow0 + r) * DMODEL + k0 + c0;
            #pragma unroll
            for (int j = 0; j < 4; ++j) a[j] = *(const short8*)(Ap + j * 8);
        } else {
            const float* Ap = (const float*)Araw + (size_t)(arow0 + r) * DMODEL + k0 + c0;
            #pragma unroll
            for (int j = 0; j < 4; ++j)
                #pragma unroll
                for (int u = 0; u < 8; ++u) a[j][u] = (short)f2bf(Ap[j * 8 + u]);
        }
        if (!b_fp32) {
            const unsigned short* Bp = (const unsigned short*)Braw + (size_t)(brow0 + r) * DMODEL + k0 + c0;
            #pragma unroll
            for (int j = 0; j < 4; ++j) b[j] = *(const short8*)(Bp + j * 8);
        } else {
            const float* Bp = (const float*)Braw + (size_t)(brow0 + r) * DMODEL + k0 + c0;
            #pragma unroll
            for (int j = 0; j < 4; ++j)
                #pragma unroll
                for (int u = 0; u < 8; ++u) b[j][u] = (short)f2bf(Bp[j * 8 + u]);
        }
    };

    stage(0, av[0], bv[0]);
    stage(128, av[1], bv[1]);
    #pragma unroll
    for (int it = 0; it < 8; ++it) {
        int pp = it & 1;
        __syncthreads();   // previous iter's LDS reads done
        #pragma unroll
        for (int j = 0; j < 4; ++j) {
            *(short8*)&As[r][c0 + j * 8] = av[pp][j];
            *(short8*)&Bs[r][c0 + j * 8] = bv[pp][j];
        }
        __syncthreads();   // LDS ready
        if (it < 6) stage((it + 2) * 128, av[pp], bv[pp]);   // distance-2 prefetch
        #pragma unroll
        for (int kk = 0; kk < 4; ++kk) {
            short8 a0 = *(const short8*)&As[mq + ml][kk * 32 + q4 * 8];
            short8 a1 = *(const short8*)&As[mq + 16 + ml][kk * 32 + q4 * 8];
            short8 b0 = *(const short8*)&Bs[nq + ml][kk * 32 + q4 * 8];
            short8 b1 = *(const short8*)&Bs[nq + 16 + ml][kk * 32 + q4 * 8];
            acc[0] = MFMA(a0, b0, acc[0]); acc[1] = MFMA(a0, b1, acc[1]);
            acc[2] = MFMA(a1, b0, acc[2]); acc[3] = MFMA(a1, b1, acc[3]);
        }
    }
}

// ---------------------------------------------------------------------------
// Kernel 1: QKV projection. grid (24, 16): nb 0..3 q, 4..7 k, 8..23 v.
// ---------------------------------------------------------------------------
__global__ __launch_bounds__(256) void qkv_gemm(
    const void* __restrict__ hidR, const void* __restrict__ WqR,
    const void* __restrict__ WkR, const void* __restrict__ WvR,
    unsigned short* __restrict__ qb, unsigned short* __restrict__ kb,
    unsigned short* __restrict__ vb) {
    int fp32 = block_detect_fp32((const unsigned short*)WqR);
    __shared__ __align__(16) unsigned short As[64][136];
    __shared__ __align__(16) unsigned short Bs[64][136];
    int nb = blockIdx.x, mb = blockIdx.y;
    const void* Braw; unsigned short* Cout; int ldc, col0, br0;
    if (nb < 4)      { Braw = WqR; br0 = nb * 64;       Cout = qb; ldc = 256;  col0 = nb * 64; }
    else if (nb < 8) { Braw = WkR; br0 = (nb - 4) * 64; Cout = kb; ldc = 256;  col0 = (nb - 4) * 64; }
    else             { Braw = WvR; br0 = (nb - 8) * 64; Cout = vb; ldc = 1024; col0 = (nb - 8) * 64; }

    floatx4 acc[4];
    gemm64_body(As, Bs, hidR, fp32, mb * 64, Braw, fp32, br0, acc);

    int wave = threadIdx.x >> 6, lane = threadIdx.x & 63;
    int ml = lane & 15, q4 = lane >> 4;
    int mq = (wave >> 1) * 32, nq = (wave & 1) * 32;
    #pragma unroll
    for (int mi = 0; mi < 2; ++mi)
        #pragma unroll
        for (int ni = 0; ni < 2; ++ni) {
            floatx4 a = acc[mi * 2 + ni];
            int nloc = nq + ni * 16 + ml;
            #pragma unroll
            for (int r4 = 0; r4 < 4; ++r4) {
                int row = mb * 64 + mq + mi * 16 + q4 * 4 + r4;
                Cout[(size_t)row * ldc + col0 + nloc] = f2bf(a[r4]);
            }
        }
}

// ---------------------------------------------------------------------------
// Kernel 2: flash-style quadratic polynomial attention with k/v prefetch.
// S(l,t) = 1 + (q.k)/4 + (q.k)^2/32, causal; y = S V / (S 1).
// Block (h, c): Q rows [64c, +64), loop kv tiles j = 0..c. q A-fragment
// hoisted out of the loop (loop-invariant; avoids post-barrier reloads).
// ---------------------------------------------------------------------------
__global__ __launch_bounds__(256) void flash_attn(
    const unsigned short* __restrict__ qb, const unsigned short* __restrict__ kb,
    const unsigned short* __restrict__ vb, unsigned short* __restrict__ ybB) {
    int h = blockIdx.x & 15, c = blockIdx.x >> 4;
    int l0 = c * CHUNK;
    __shared__ __align__(16) unsigned short qs[64][40];
    __shared__ __align__(16) unsigned short ksm[64][40];
    __shared__ __align__(16) unsigned short vT[80][72];   // rows 0..63 v^T, 64 ones
    __shared__ __align__(16) unsigned short P[64][72];
    int t = threadIdx.x, lane = t & 63, wave = t >> 6;
    int ml = lane & 15, q4 = lane >> 4;
    int m0 = wave * 16;
    int sm = t >> 2, si4 = (t & 3) * 4, scc = (t & 3) * 16;

    // ---- one-time staging: q rows (zero-padded K=32), k pad, vT pad rows
    {
        *(ushort4*)&qs[sm][si4] = *(const ushort4*)&qb[(size_t)(l0 + sm) * 256 + h * 16 + si4];
        ushort4 z = {0, 0, 0, 0};
        *(ushort4*)&qs[sm][16 + si4]  = z;
        *(ushort4*)&ksm[sm][16 + si4] = z;   // k pad, persists across tiles
    }
    if (t < 64) {
        vT[64][t] = 0x3F80;   // 1.0 bf16 (denominator row)
        #pragma unroll
        for (int i = 65; i < 80; ++i) vT[i][t] = 0;
    }

    auto load_kv = [&](int j, ushort4& kr, ushort4 vr[4]) {
        kr = *(const ushort4*)&kb[(size_t)(j * 64 + sm) * 256 + h * 16 + si4];
        #pragma unroll
        for (int u = 0; u < 4; ++u)
            vr[u] = *(const ushort4*)&vb[(size_t)(j * 64 + sm) * 1024 + h * 64 + scc + u * 4];
    };

    floatx4 acc[5];
    #pragma unroll
    for (int i = 0; i < 5; ++i) acc[i] = (floatx4){0.f, 0.f, 0.f, 0.f};

    ushort4 kr, vr[4], kr2, vr2[4];
    load_kv(0, kr, vr);

    __syncthreads();   // qs staged -> hoist the loop-invariant q fragment
    short8 aq = *(const short8*)&qs[m0 + ml][q4 * 8];

    for (int j = 0; j <= c; ++j) {
        // ---- write prefetched k_j / v_j^T to LDS
        {
            *(ushort4*)&ksm[sm][si4] = kr;
            unsigned short tmp[16];
            #pragma unroll
            for (int u = 0; u < 4; ++u) *(ushort4*)&tmp[u * 4] = vr[u];
            #pragma unroll
            for (int u = 0; u < 16; ++u) vT[scc + u][sm] = tmp[u];
        }
        __syncthreads();   // staging visible
        if (j < c) load_kv(j + 1, kr2, vr2);   // overlap with MFMAs below

        // ---- scores S = q k^T (K=32, zero-padded), poly + causal -> P
        bool diag = (j == c);
        #pragma unroll
        for (int nt = 0; nt < 4; ++nt) {
            short8 bk = *(const short8*)&ksm[nt * 16 + ml][q4 * 8];
            floatx4 s4 = {0.f, 0.f, 0.f, 0.f};
            s4 = MFMA(aq, bk, s4);
            int tt = nt * 16 + ml;
            #pragma unroll
            for (int r = 0; r < 4; ++r) {
                int lrow = m0 + q4 * 4 + r;
                float s = s4[r];
                float p = 1.f + 0.25f * s + 0.03125f * s * s;
                if (diag && tt > lrow) p = 0.f;
                P[lrow][tt] = f2bf(p);
            }
        }
        // P rows are wave-private (written rows m0..m0+15, read rows m0+ml):
        // no barrier needed before PV.

        // ---- PV: acc[nt] += P x vT (nt=4 ones-row -> denominator)
        #pragma unroll
        for (int k0 = 0; k0 < 64; k0 += 32) {
            short8 ap = *(const short8*)&P[m0 + ml][k0 + q4 * 8];
            #pragma unroll
            for (int nt = 0; nt < 5; ++nt) {
                short8 bvv = *(const short8*)&vT[nt * 16 + ml][k0 + q4 * 8];
                acc[nt] = MFMA(ap, bvv, acc[nt]);
            }
        }
        __syncthreads();   // protect ksm/vT from next tile's staging
        kr = kr2;
        #pragma unroll
        for (int u = 0; u < 4; ++u) vr[u] = vr2[u];
    }

    // ---- epilogue: den broadcast via shfl; y = num/den -> bf16
    #pragma unroll
    for (int r = 0; r < 4; ++r) {
        float den = __shfl(acc[4][r], q4 * 16) + 1e-12f;
        float dinv = 1.f / den;
        int lrow = m0 + q4 * 4 + r;
        unsigned short* yp = ybB + (size_t)(l0 + lrow) * 1024 + h * 64;
        #pragma unroll
        for (int nt = 0; nt < 4; ++nt)
            yp[nt * 16 + ml] = f2bf(acc[nt][r] * dinv);
    }
}

// ---------------------------------------------------------------------------
// Kernel 3: output projection. out = y @ Wo^T (1024^3). Output dtype per
// detector.
// ---------------------------------------------------------------------------
__global__ __launch_bounds__(256) void out_gemm(
    const unsigned short* __restrict__ A, const void* __restrict__ WoR,
    void* __restrict__ outv, const unsigned short* __restrict__ wqraw) {
    int fp32 = block_detect_fp32(wqraw);
    __shared__ __align__(16) unsigned short As[64][136];
    __shared__ __align__(16) unsigned short Bs[64][136];
    int nb = blockIdx.x, mb = blockIdx.y;

    floatx4 acc[4];
    gemm64_body(As, Bs, A, 0, mb * 64, WoR, fp32, nb * 64, acc);

    int wave = threadIdx.x >> 6, lane = threadIdx.x & 63;
    int ml = lane & 15, q4 = lane >> 4;
    int mq = (wave >> 1) * 32, nq = (wave & 1) * 32;
    #pragma unroll
    for (int mi = 0; mi < 2; ++mi)
        #pragma unroll
        for (int ni = 0; ni < 2; ++ni) {
            floatx4 a = acc[mi * 2 + ni];
            int n = nb * 64 + nq + ni * 16 + ml;
            #pragma unroll
            for (int r4 = 0; r4 < 4; ++r4) {
                int row = mb * 64 + mq + mi * 16 + q4 * 4 + r4;
                size_t idx = (size_t)row * 1024 + n;
                if (fp32) ((float*)outv)[idx] = a[r4];
                else      ((unsigned short*)outv)[idx] = f2bf(a[r4]);
            }
        }
}

// ---------------------------------------------------------------------------
extern "C" void kernel_launch(void* const* d_in, const int* in_sizes, int n_in,
                              void* d_out, int out_size, void* d_ws, size_t ws_size,
                              hipStream_t stream) {
    unsigned short* us = (unsigned short*)d_ws;
    unsigned short* qbB = us + U_QB;
    unsigned short* kbB = us + U_KB;
    unsigned short* vbB = us + U_VB;
    unsigned short* ybB = us + U_YB;
    size_t need = (size_t)(U_YB + 1048576) * 2ull;
    if (ws_size < need) return;

    qkv_gemm<<<dim3(24, 16), 256, 0, stream>>>(d_in[0], d_in[1], d_in[2], d_in[3], qbB, kbB, vbB);
    flash_attn<<<dim3(256), 256, 0, stream>>>(qbB, kbB, vbB, ybB);
    out_gemm<<<dim3(16, 16), 256, 0, stream>>>(ybB, d_in[4], d_out, (const unsigned short*)d_in[1]);
}